// Round 3
// baseline (601.446 us; speedup 1.0000x reference)
//
#include <hip/hip_runtime.h>
#include <hip/hip_bf16.h>
#include <math.h>

// Problem dims
#define BB 8
#define AA 128
#define TT 128
#define DD 256
#define NBA (BB*AA)   // 1024 (b,a) pairs
#define DFC 1024      // 4*D

typedef __attribute__((ext_vector_type(8))) short short8;
typedef __attribute__((ext_vector_type(4))) float f32x4;
typedef __attribute__((ext_vector_type(4))) unsigned short ushort4v;

static __device__ __forceinline__ unsigned short f2bf(float f) {
  union { float f; unsigned u; } v; v.f = f;
  unsigned r = v.u + 0x7FFFu + ((v.u >> 16) & 1u);
  return (unsigned short)(r >> 16);
}
static __device__ __forceinline__ float bf2f(unsigned short h) {
  union { unsigned u; float f; } v; v.u = ((unsigned)h) << 16;
  return v.f;
}
static __device__ __forceinline__ float wsum(float s) {
  #pragma unroll
  for (int off = 32; off > 0; off >>= 1) s += __shfl_xor(s, off);
  return s;
}
static __device__ __forceinline__ float gelu_exact(float x) {
  return 0.5f * x * (1.0f + erff(x * 0.7071067811865475f));
}

// ---------------------------------------------------------------------------
// K0: repack weights to bf16 in MFMA B-fragment order.
// W1S (from w_fc, 256x1024): frag t in [0,32768): l=t&63, ks=(t>>6)&7, ntg=t>>9
//   element e: B[k][n] with n=ntg*16+(l&15), k=ks*32+(l>>4)*8+e  -> w1s[t*8+e]
// W2S (from w_pr, 1024x256): frag u in [0,32768): l=u&63, ksg=(u>>6)&31, ntg=u>>11
//   element e: B[k][n] with n=ntg*16+(l&15), k=ksg*32+(l>>4)*8+e -> w2s[u*8+e]
// ---------------------------------------------------------------------------
__global__ void prep_weights(const float* __restrict__ w_fc,
                             const float* __restrict__ w_pr,
                             unsigned short* __restrict__ w1s,
                             unsigned short* __restrict__ w2s) {
  int t = blockIdx.x * blockDim.x + threadIdx.x;   // 0..65535
  if (t < 32768) {
    int l = t & 63, ks = (t >> 6) & 7, ntg = t >> 9;
    int n = ntg * 16 + (l & 15);
    int kb = ks * 32 + (l >> 4) * 8;
    short8 v;
    #pragma unroll
    for (int e = 0; e < 8; ++e)
      v[e] = (short)f2bf(w_fc[(size_t)(kb + e) * DFC + n]);
    *(short8*)(w1s + (size_t)t * 8) = v;
  } else {
    int u = t - 32768;
    int l = u & 63, ksg = (u >> 6) & 31, ntg = u >> 11;
    int n = ntg * 16 + (l & 15);
    int kb = ksg * 32 + (l >> 4) * 8;
    short8 v;
    #pragma unroll
    for (int e = 0; e < 8; ++e)
      v[e] = (short)f2bf(w_pr[(size_t)(kb + e) * DD + n]);
    *(short8*)(w2s + (size_t)u * 8) = v;
  }
}

// ---------------------------------------------------------------------------
// K1: attn_out[r,:] = (cx[r,:] @ wkv[:,D:2D] + bkv[D:2D]) @ wo + bo
// One block per (b,a) row; 256 threads.
// ---------------------------------------------------------------------------
__global__ void attn_out_kernel(const float* __restrict__ cx,
                                const float* __restrict__ wkv,
                                const float* __restrict__ bkv,
                                const float* __restrict__ wo,
                                const float* __restrict__ bo,
                                float* __restrict__ attn) {
  __shared__ float s_cx[DD];
  __shared__ float s_v[DD];
  const int r = blockIdx.x;
  const int t = threadIdx.x;
  s_cx[t] = cx[(size_t)r * DD + t];
  __syncthreads();
  float acc = bkv[DD + t];
  #pragma unroll 4
  for (int k = 0; k < DD; ++k)
    acc += s_cx[k] * wkv[(size_t)k * (2 * DD) + DD + t];
  s_v[t] = acc;
  __syncthreads();
  float acc2 = bo[t];
  #pragma unroll 4
  for (int k = 0; k < DD; ++k)
    acc2 += s_v[k] * wo[(size_t)k * DD + t];
  attn[(size_t)r * DD + t] = acc2;
}

// ---------------------------------------------------------------------------
// K2: per (b,a) block: LN1 -> +attn_out -> LN2 -> fused MLP (bf16 MFMA)
// 512 threads = 8 waves, arranged 2(M) x 4(N).
// ---------------------------------------------------------------------------
__global__ __launch_bounds__(512, 2)
void fused_block(const float* __restrict__ x,
                 const float* __restrict__ ln1_w, const float* __restrict__ ln1_b,
                 const float* __restrict__ ln2_w, const float* __restrict__ ln2_b,
                 const float* __restrict__ attn,
                 const unsigned short* __restrict__ w1s,
                 const unsigned short* __restrict__ w2s,
                 const float* __restrict__ b_fc, const float* __restrict__ b_pr,
                 float* __restrict__ out) {
  // x3 tile: 128 rows x 256 cols bf16, row stride 264 (132 dwords == 4 mod 32:
  // each 8-lane b128 phase covers all 32 banks -> conflict-free)
  __shared__ unsigned short sx3[128 * 264];   // 67584 B
  // h chunk: 128 rows x 128 cols bf16, row stride 136 (68 dwords == 4 mod 32)
  __shared__ unsigned short sh[128 * 136];    // 34816 B

  const int bid = blockIdx.x;
  const int tid = threadIdx.x;
  const int l = tid & 63;
  const int w = tid >> 6;

  const float* xp = x + (size_t)bid * (TT * DD);
  float* outp = out + (size_t)bid * (TT * DD);

  // ---------------- Phase A: LN1 + attn add + LN2 -> sx3 (bf16) -------------
  {
    const int col = 4 * l;                       // each lane owns 4 cols
    const float4 w1v = *(const float4*)(ln1_w + col);
    const float4 b1v = *(const float4*)(ln1_b + col);
    const float4 w2v = *(const float4*)(ln2_w + col);
    const float4 b2v = *(const float4*)(ln2_b + col);
    const float4 aov = *(const float4*)(attn + (size_t)bid * DD + col);

    for (int j = 0; j < 16; ++j) {
      const int row = w + 8 * j;                 // wave w handles rows w+8j
      float4 v = *(const float4*)(xp + (size_t)row * DD + col);
      // LN1
      float mu = wsum(v.x + v.y + v.z + v.w) * (1.0f / DD);
      float d0 = v.x - mu, d1 = v.y - mu, d2 = v.z - mu, d3 = v.w - mu;
      float rstd = rsqrtf(wsum(d0*d0 + d1*d1 + d2*d2 + d3*d3) * (1.0f / DD) + 1e-5f);
      // x2 = x1 + attn_out
      float x20 = d0 * rstd * w1v.x + b1v.x + aov.x;
      float x21 = d1 * rstd * w1v.y + b1v.y + aov.y;
      float x22 = d2 * rstd * w1v.z + b1v.z + aov.z;
      float x23 = d3 * rstd * w1v.w + b1v.w + aov.w;
      // LN2
      float mu2 = wsum(x20 + x21 + x22 + x23) * (1.0f / DD);
      float e0 = x20 - mu2, e1 = x21 - mu2, e2 = x22 - mu2, e3 = x23 - mu2;
      float rstd2 = rsqrtf(wsum(e0*e0 + e1*e1 + e2*e2 + e3*e3) * (1.0f / DD) + 1e-5f);
      ushort4v pk;
      pk.x = f2bf(e0 * rstd2 * w2v.x + b2v.x);
      pk.y = f2bf(e1 * rstd2 * w2v.y + b2v.y);
      pk.z = f2bf(e2 * rstd2 * w2v.z + b2v.z);
      pk.w = f2bf(e3 * rstd2 * w2v.w + b2v.w);
      *(ushort4v*)(sx3 + (size_t)row * 264 + col) = pk;
    }
  }
  __syncthreads();

  // ---------------- Phase B: fused MLP ------------------------------------
  const int wm = w >> 2;       // 0..1  (64-row group)
  const int wn = w & 3;        // 0..3  (N group)
  const int lr = l & 15;
  const int lk = l >> 4;

  f32x4 acc2[4][4];
  #pragma unroll
  for (int mt = 0; mt < 4; ++mt)
    #pragma unroll
    for (int nt = 0; nt < 4; ++nt)
      acc2[mt][nt] = (f32x4)0.0f;

  for (int c = 0; c < 8; ++c) {
    // --- GEMM1: h_c[128 x 128] = x3 @ w_fc[:, c*128 : c*128+128] ---
    f32x4 acc1[4][2];
    #pragma unroll
    for (int mt = 0; mt < 4; ++mt) { acc1[mt][0] = (f32x4)0.0f; acc1[mt][1] = (f32x4)0.0f; }

    #pragma unroll
    for (int ks = 0; ks < 8; ++ks) {
      short8 a[4];
      #pragma unroll
      for (int mt = 0; mt < 4; ++mt)
        a[mt] = *(const short8*)(sx3 + (size_t)(64*wm + mt*16 + lr) * 264 + ks*32 + lk*8);
      #pragma unroll
      for (int nt = 0; nt < 2; ++nt) {
        const int ntg = c*8 + wn*2 + nt;
        short8 b = *(const short8*)(w1s + ((size_t)(ntg*8 + ks) * 64 + l) * 8);
        #pragma unroll
        for (int mt = 0; mt < 4; ++mt)
          acc1[mt][nt] = __builtin_amdgcn_mfma_f32_16x16x32_bf16(a[mt], b, acc1[mt][nt], 0, 0, 0);
      }
    }

    __syncthreads();   // prev chunk's GEMM2 reads of sh are done

    // bias + gelu -> sh (bf16)
    #pragma unroll
    for (int nt = 0; nt < 2; ++nt) {
      const int hcol = wn*32 + nt*16 + lr;
      const float bias = b_fc[c*128 + hcol];
      #pragma unroll
      for (int mt = 0; mt < 4; ++mt)
        #pragma unroll
        for (int r = 0; r < 4; ++r) {
          const int hrow = 64*wm + mt*16 + lk*4 + r;
          sh[(size_t)hrow * 136 + hcol] = f2bf(gelu_exact(acc1[mt][nt][r] + bias));
        }
    }
    __syncthreads();   // sh ready for all waves

    // --- GEMM2 partial: acc2 += h_c @ w_pr[c*128 : c*128+128, :] ---
    #pragma unroll
    for (int ks = 0; ks < 4; ++ks) {
      short8 a[4];
      #pragma unroll
      for (int mt = 0; mt < 4; ++mt)
        a[mt] = *(const short8*)(sh + (size_t)(64*wm + mt*16 + lr) * 136 + ks*32 + lk*8);
      #pragma unroll
      for (int nt = 0; nt < 4; ++nt) {
        const int ntg = wn*4 + nt;
        short8 b = *(const short8*)(w2s + ((size_t)(ntg*32 + c*4 + ks) * 64 + l) * 8);
        #pragma unroll
        for (int mt = 0; mt < 4; ++mt)
          acc2[mt][nt] = __builtin_amdgcn_mfma_f32_16x16x32_bf16(a[mt], b, acc2[mt][nt], 0, 0, 0);
      }
    }
  }

  // ---------------- Epilogue: out = x3 + mlp + b_pr ------------------------
  #pragma unroll
  for (int nt = 0; nt < 4; ++nt) {
    const int colg = wn*64 + nt*16 + lr;
    const float bp = b_pr[colg];
    #pragma unroll
    for (int mt = 0; mt < 4; ++mt)
      #pragma unroll
      for (int r = 0; r < 4; ++r) {
        const int row = 64*wm + mt*16 + lk*4 + r;
        outp[(size_t)row * DD + colg] = bf2f(sx3[(size_t)row * 264 + colg]) + acc2[mt][nt][r] + bp;
      }
  }
}

// ---------------------------------------------------------------------------
extern "C" void kernel_launch(void* const* d_in, const int* in_sizes, int n_in,
                              void* d_out, int out_size, void* d_ws, size_t ws_size,
                              hipStream_t stream) {
  const float* x     = (const float*)d_in[0];
  const float* cx    = (const float*)d_in[1];
  const float* ln1_w = (const float*)d_in[2];
  const float* ln1_b = (const float*)d_in[3];
  // d_in[4]=wq, d_in[5]=bq: provably unused (softmax over identical logits
  // makes att@V == V exactly)
  const float* wkv   = (const float*)d_in[6];
  const float* bkv   = (const float*)d_in[7];
  const float* wo    = (const float*)d_in[8];
  const float* bo    = (const float*)d_in[9];
  const float* ln2_w = (const float*)d_in[10];
  const float* ln2_b = (const float*)d_in[11];
  const float* w_fc  = (const float*)d_in[12];
  const float* b_fc  = (const float*)d_in[13];
  const float* w_pr  = (const float*)d_in[14];
  const float* b_pr  = (const float*)d_in[15];

  unsigned short* w1s = (unsigned short*)d_ws;             // 1024*256 bf16
  unsigned short* w2s = w1s + 1024 * 256;                  // 256*1024 bf16
  float* attn = (float*)(w2s + 256 * 1024);                // 1024*256 f32

  prep_weights<<<dim3(256), dim3(256), 0, stream>>>(w_fc, w_pr, w1s, w2s);
  attn_out_kernel<<<dim3(NBA), dim3(256), 0, stream>>>(cx, wkv, bkv, wo, bo, attn);
  fused_block<<<dim3(NBA), dim3(512), 0, stream>>>(x, ln1_w, ln1_b, ln2_w, ln2_b,
                                                   attn, w1s, w2s, b_fc, b_pr,
                                                   (float*)d_out);
}

// Round 5
// 564.968 us; speedup vs baseline: 1.0646x; 1.0646x over previous
//
#include <hip/hip_runtime.h>
#include <hip/hip_bf16.h>
#include <math.h>

// Problem dims
#define BB 8
#define AA 128
#define TT 128
#define DD 256
#define NBA (BB*AA)   // 1024 (b,a) pairs
#define DFC 1024      // 4*D

typedef __attribute__((ext_vector_type(8))) short short8;
typedef __attribute__((ext_vector_type(4))) float f32x4;
typedef __attribute__((ext_vector_type(4))) unsigned short ushort4v;

static __device__ __forceinline__ unsigned short f2bf(float f) {
  union { float f; unsigned u; } v; v.f = f;
  unsigned r = v.u + 0x7FFFu + ((v.u >> 16) & 1u);
  return (unsigned short)(r >> 16);
}
static __device__ __forceinline__ float bf2f(unsigned short h) {
  union { unsigned u; float f; } v; v.u = ((unsigned)h) << 16;
  return v.f;
}
static __device__ __forceinline__ float wsum(float s) {
  #pragma unroll
  for (int off = 32; off > 0; off >>= 1) s += __shfl_xor(s, off);
  return s;
}
static __device__ __forceinline__ float gelu_exact(float x) {
  return 0.5f * x * (1.0f + erff(x * 0.7071067811865475f));
}

// ---------------------------------------------------------------------------
// K0: repack weights to bf16 in MFMA B-fragment order (unchanged from r0).
// ---------------------------------------------------------------------------
__global__ void prep_weights(const float* __restrict__ w_fc,
                             const float* __restrict__ w_pr,
                             unsigned short* __restrict__ w1s,
                             unsigned short* __restrict__ w2s) {
  int t = blockIdx.x * blockDim.x + threadIdx.x;   // 0..65535
  if (t < 32768) {
    int l = t & 63, ks = (t >> 6) & 7, ntg = t >> 9;
    int n = ntg * 16 + (l & 15);
    int kb = ks * 32 + (l >> 4) * 8;
    short8 v;
    #pragma unroll
    for (int e = 0; e < 8; ++e)
      v[e] = (short)f2bf(w_fc[(size_t)(kb + e) * DFC + n]);
    *(short8*)(w1s + (size_t)t * 8) = v;
  } else {
    int u = t - 32768;
    int l = u & 63, ksg = (u >> 6) & 31, ntg = u >> 11;
    int n = ntg * 16 + (l & 15);
    int kb = ksg * 32 + (l >> 4) * 8;
    short8 v;
    #pragma unroll
    for (int e = 0; e < 8; ++e)
      v[e] = (short)f2bf(w_pr[(size_t)(kb + e) * DD + n]);
    *(short8*)(w2s + (size_t)u * 8) = v;
  }
}

// ---------------------------------------------------------------------------
// K1: attn_out[r,:] = (cx[r,:] @ wkv[:,D:2D] + bkv[D:2D]) @ wo + bo
// ---------------------------------------------------------------------------
__global__ void attn_out_kernel(const float* __restrict__ cx,
                                const float* __restrict__ wkv,
                                const float* __restrict__ bkv,
                                const float* __restrict__ wo,
                                const float* __restrict__ bo,
                                float* __restrict__ attn) {
  __shared__ float s_cx[DD];
  __shared__ float s_v[DD];
  const int r = blockIdx.x;
  const int t = threadIdx.x;
  s_cx[t] = cx[(size_t)r * DD + t];
  __syncthreads();
  float acc = bkv[DD + t];
  #pragma unroll 4
  for (int k = 0; k < DD; ++k)
    acc += s_cx[k] * wkv[(size_t)k * (2 * DD) + DD + t];
  s_v[t] = acc;
  __syncthreads();
  float acc2 = bo[t];
  #pragma unroll 4
  for (int k = 0; k < DD; ++k)
    acc2 += s_v[k] * wo[(size_t)k * DD + t];
  attn[(size_t)r * DD + t] = acc2;
}

// ---------------------------------------------------------------------------
// K2: 64-row tile per block, 256 threads = 4 waves (wn = wave id, N-split).
// LDS 50.7 KB -> 3 blocks/CU (12 waves/CU) for cross-block latency hiding.
// ---------------------------------------------------------------------------
__global__ __launch_bounds__(256, 3)
void fused_block(const float* __restrict__ x,
                 const float* __restrict__ ln1_w, const float* __restrict__ ln1_b,
                 const float* __restrict__ ln2_w, const float* __restrict__ ln2_b,
                 const float* __restrict__ attn,
                 const unsigned short* __restrict__ w1s,
                 const unsigned short* __restrict__ w2s,
                 const float* __restrict__ b_fc, const float* __restrict__ b_pr,
                 float* __restrict__ out) {
  // sx3: 64 rows x 256 cols bf16, stride 264 (132 dw == 4 mod 32: b128 reads
  // conflict-free, b64 phase-A writes conflict-free)
  __shared__ unsigned short sx3[64 * 264];   // 33792 B
  // sh: 64 rows x 128 cols bf16, stride 132 (66 dw == 2 mod 32: b16 gelu
  // writes spread over all 32 banks = 2-way free; b128 reads <=2-way)
  __shared__ unsigned short sh[64 * 132];    // 16896 B

  const int bid = blockIdx.x;
  const int ba   = bid >> 1;        // (b,a) pair
  const int half = bid & 1;         // which 64-row half of T
  const int tid = threadIdx.x;
  const int l = tid & 63;
  const int w = tid >> 6;           // 0..3

  const float* xp = x + ((size_t)ba * TT + half * 64) * DD;
  float* outp = out + ((size_t)ba * TT + half * 64) * DD;

  // ---------------- Phase A: LN1 + attn add + LN2 -> sx3 (bf16) -------------
  {
    const int col = 4 * l;                       // each lane owns 4 cols
    const float4 w1v = *(const float4*)(ln1_w + col);
    const float4 b1v = *(const float4*)(ln1_b + col);
    const float4 w2v = *(const float4*)(ln2_w + col);
    const float4 b2v = *(const float4*)(ln2_b + col);
    const float4 aov = *(const float4*)(attn + (size_t)ba * DD + col);

    for (int j = 0; j < 16; ++j) {
      const int row = w + 4 * j;                 // wave w handles rows w+4j
      float4 v = *(const float4*)(xp + (size_t)row * DD + col);
      // LN1
      float mu = wsum(v.x + v.y + v.z + v.w) * (1.0f / DD);
      float d0 = v.x - mu, d1 = v.y - mu, d2 = v.z - mu, d3 = v.w - mu;
      float rstd = rsqrtf(wsum(d0*d0 + d1*d1 + d2*d2 + d3*d3) * (1.0f / DD) + 1e-5f);
      // x2 = x1 + attn_out
      float x20 = d0 * rstd * w1v.x + b1v.x + aov.x;
      float x21 = d1 * rstd * w1v.y + b1v.y + aov.y;
      float x22 = d2 * rstd * w1v.z + b1v.z + aov.z;
      float x23 = d3 * rstd * w1v.w + b1v.w + aov.w;
      // LN2
      float mu2 = wsum(x20 + x21 + x22 + x23) * (1.0f / DD);
      float e0 = x20 - mu2, e1 = x21 - mu2, e2 = x22 - mu2, e3 = x23 - mu2;
      float rstd2 = rsqrtf(wsum(e0*e0 + e1*e1 + e2*e2 + e3*e3) * (1.0f / DD) + 1e-5f);
      ushort4v pk;
      pk.x = f2bf(e0 * rstd2 * w2v.x + b2v.x);
      pk.y = f2bf(e1 * rstd2 * w2v.y + b2v.y);
      pk.z = f2bf(e2 * rstd2 * w2v.z + b2v.z);
      pk.w = f2bf(e3 * rstd2 * w2v.w + b2v.w);
      *(ushort4v*)(sx3 + (size_t)row * 264 + col) = pk;
    }
  }
  __syncthreads();

  // ---------------- Phase B: fused MLP ------------------------------------
  const int wn = w;            // 0..3 (N group)
  const int lr = l & 15;
  const int lk = l >> 4;

  f32x4 acc2[4][4];
  #pragma unroll
  for (int mt = 0; mt < 4; ++mt)
    #pragma unroll
    for (int nt = 0; nt < 4; ++nt)
      acc2[mt][nt] = (f32x4)0.0f;

  for (int c = 0; c < 8; ++c) {
    // --- GEMM1: h_c[64 x 128] = x3 @ w_fc[:, c*128 : c*128+128] ---
    f32x4 acc1[4][2];
    #pragma unroll
    for (int mt = 0; mt < 4; ++mt) { acc1[mt][0] = (f32x4)0.0f; acc1[mt][1] = (f32x4)0.0f; }

    #pragma unroll
    for (int ks = 0; ks < 8; ++ks) {
      short8 a[4];
      #pragma unroll
      for (int mt = 0; mt < 4; ++mt)
        a[mt] = *(const short8*)(sx3 + (size_t)(mt*16 + lr) * 264 + ks*32 + lk*8);
      #pragma unroll
      for (int nt = 0; nt < 2; ++nt) {
        const int ntg = c*8 + wn*2 + nt;
        short8 b = *(const short8*)(w1s + ((size_t)(ntg*8 + ks) * 64 + l) * 8);
        #pragma unroll
        for (int mt = 0; mt < 4; ++mt)
          acc1[mt][nt] = __builtin_amdgcn_mfma_f32_16x16x32_bf16(a[mt], b, acc1[mt][nt], 0, 0, 0);
      }
    }

    __syncthreads();   // prev chunk's GEMM2 reads of sh are done

    // bias + gelu -> sh (bf16)
    #pragma unroll
    for (int nt = 0; nt < 2; ++nt) {
      const int hcol = wn*32 + nt*16 + lr;
      const float bias = b_fc[c*128 + hcol];
      #pragma unroll
      for (int mt = 0; mt < 4; ++mt)
        #pragma unroll
        for (int r = 0; r < 4; ++r) {
          const int hrow = mt*16 + lk*4 + r;
          sh[(size_t)hrow * 132 + hcol] = f2bf(gelu_exact(acc1[mt][nt][r] + bias));
        }
    }
    __syncthreads();   // sh ready for all waves

    // --- GEMM2 partial: acc2 += h_c @ w_pr[c*128 : c*128+128, :] ---
    #pragma unroll
    for (int ks = 0; ks < 4; ++ks) {
      short8 a[4];
      #pragma unroll
      for (int mt = 0; mt < 4; ++mt)
        a[mt] = *(const short8*)(sh + (size_t)(mt*16 + lr) * 132 + ks*32 + lk*8);
      #pragma unroll
      for (int nt = 0; nt < 4; ++nt) {
        const int ntg = wn*4 + nt;
        short8 b = *(const short8*)(w2s + ((size_t)(ntg*32 + c*4 + ks) * 64 + l) * 8);
        #pragma unroll
        for (int mt = 0; mt < 4; ++mt)
          acc2[mt][nt] = __builtin_amdgcn_mfma_f32_16x16x32_bf16(a[mt], b, acc2[mt][nt], 0, 0, 0);
      }
    }
  }

  // ---------------- Epilogue: out = x3 + mlp + b_pr ------------------------
  #pragma unroll
  for (int nt = 0; nt < 4; ++nt) {
    const int colg = wn*64 + nt*16 + lr;
    const float bp = b_pr[colg];
    #pragma unroll
    for (int mt = 0; mt < 4; ++mt)
      #pragma unroll
      for (int r = 0; r < 4; ++r) {
        const int row = mt*16 + lk*4 + r;
        outp[(size_t)row * DD + colg] = bf2f(sx3[(size_t)row * 264 + colg]) + acc2[mt][nt][r] + bp;
      }
  }
}

// ---------------------------------------------------------------------------
extern "C" void kernel_launch(void* const* d_in, const int* in_sizes, int n_in,
                              void* d_out, int out_size, void* d_ws, size_t ws_size,
                              hipStream_t stream) {
  const float* x     = (const float*)d_in[0];
  const float* cx    = (const float*)d_in[1];
  const float* ln1_w = (const float*)d_in[2];
  const float* ln1_b = (const float*)d_in[3];
  // d_in[4]=wq, d_in[5]=bq: provably unused (uniform softmax -> att@V == V)
  const float* wkv   = (const float*)d_in[6];
  const float* bkv   = (const float*)d_in[7];
  const float* wo    = (const float*)d_in[8];
  const float* bo    = (const float*)d_in[9];
  const float* ln2_w = (const float*)d_in[10];
  const float* ln2_b = (const float*)d_in[11];
  const float* w_fc  = (const float*)d_in[12];
  const float* b_fc  = (const float*)d_in[13];
  const float* w_pr  = (const float*)d_in[14];
  const float* b_pr  = (const float*)d_in[15];

  unsigned short* w1s = (unsigned short*)d_ws;             // 1024*256 bf16
  unsigned short* w2s = w1s + 1024 * 256;                  // 256*1024 bf16
  float* attn = (float*)(w2s + 256 * 1024);                // 1024*256 f32

  prep_weights<<<dim3(256), dim3(256), 0, stream>>>(w_fc, w_pr, w1s, w2s);
  attn_out_kernel<<<dim3(NBA), dim3(256), 0, stream>>>(cx, wkv, bkv, wo, bo, attn);
  fused_block<<<dim3(2 * NBA), dim3(256), 0, stream>>>(x, ln1_w, ln1_b, ln2_w, ln2_b,
                                                       attn, w1s, w2s, b_fc, b_pr,
                                                       (float*)d_out);
}